// Round 16
// baseline (260.325 us; speedup 1.0000x reference)
//
#include <hip/hip_runtime.h>
#include <hip/hip_bf16.h>
#include <math.h>

#define NROWS 8192
#define EMB   300
#define KPAD  320   // padded feature/K dim
#define NCLS  128
#define TINV  10.0f // 1/TEMP
#define LR_BLOCKS 512
#define NKC   10    // K-chunks of 32 (KPAD/32)
#define CH    512   // shorts per packed chunk (16 rows x 32 k)

typedef __attribute__((ext_vector_type(8))) short short8;
typedef __attribute__((ext_vector_type(4))) float f32x4;

// Packed fragment layout: chunk c = rowtile*NKC + k/32 holds 16 rows x 32 k,
// lane l reads row (l&15), k-sub (l>>4)*8 as one contiguous short8.
__device__ __forceinline__ size_t pk(int r, int k)
{
  return ((size_t)(r >> 4) * NKC + (k >> 5)) * CH
       + (size_t)(((k & 31) >> 3) * 16 + (r & 15)) * 8 + (k & 7);
}

__device__ __forceinline__ void split_bf16(float v, short& hi, short& lo)
{
  __hip_bfloat16 h = __float2bfloat16(v);
  __hip_bfloat16 l = __float2bfloat16(v - __bfloat162float(h));
  hi = *(short*)&h;
  lo = *(short*)&l;
}

// ---------------------------------------------------------------------------
// Cast X -> packed split planes. 512 blocks x 16 rows (was 8192 tiny WGs).
// ---------------------------------------------------------------------------
__global__ __launch_bounds__(320)
void conv_x(const float* __restrict__ X, short* __restrict__ Xh,
            short* __restrict__ Xl)
{
  int c = threadIdx.x;
  #pragma unroll
  for (int rr = 0; rr < 16; ++rr) {
    int r = blockIdx.x * 16 + rr;
    float v = (c < EMB) ? X[(size_t)r * EMB + c] : 0.f;
    short h, l;
    split_bf16(v, h, l);
    size_t o = pk(r, c);
    Xh[o] = h;
    Xl[o] = l;
  }
}

// ---------------------------------------------------------------------------
// Transpose+cast W (k-major) -> packed split planes (row = n, contiguous k).
// ---------------------------------------------------------------------------
__global__ __launch_bounds__(320)
void conv_wt(const float* __restrict__ W, short* __restrict__ Wh,
             short* __restrict__ Wl)
{
  int n = blockIdx.x, k = threadIdx.x;
  float v = (n < EMB && k < EMB) ? W[(size_t)k * EMB + n] : 0.f;
  short h, l;
  split_bf16(v, h, l);
  size_t o = pk(n, k);
  Wh[o] = h;
  Wl[o] = l;
}

#define LOADP(dst, base, rt0, kt)                                             \
  _Pragma("unroll")                                                           \
  for (int m_ = 0; m_ < 4; ++m_)                                              \
    dst[m_] = *(const short8*)((base) +                                       \
      (((size_t)(rt0) + m_) * NKC + (kt)) * CH + (size_t)lane * 8);

#define LOADP8(dst, base, rt0, kt)                                            \
  _Pragma("unroll")                                                           \
  for (int m_ = 0; m_ < 8; ++m_)                                              \
    dst[m_] = *(const short8*)((base) +                                       \
      (((size_t)(rt0) + m_) * NKC + (kt)) * CH + (size_t)lane * 8);

// ---------------------------------------------------------------------------
// Split-bf16 MFMA GEMM on packed operands (fp32-quality, Markidis 3-term).
// One wave per block, tile 64x64, grid (128, 5). Register double-buffered.
// C/D layout: col = lane&15, row = (lane>>4)*4 + reg.
// ---------------------------------------------------------------------------
template<int RELU, int OUTSPLIT>
__global__ __launch_bounds__(64)
void gemm_mfma3p(const short* __restrict__ Ahp, const short* __restrict__ Alp,
                 const short* __restrict__ Bhp, const short* __restrict__ Blp,
                 const float* __restrict__ bias,
                 float* __restrict__ Cf, short* __restrict__ Chp,
                 short* __restrict__ Clp)
{
  const int lane = threadIdx.x;
  const int i0   = blockIdx.x * 64;
  const int j0   = blockIdx.y * 64;
  const int rta  = i0 >> 4;
  const int ntb  = j0 >> 4;
  const int jc   = lane & 15;
  const int rq   = (lane >> 4) * 4;

  f32x4 acc[4][4] = {};
  short8 ah[2][4], al[2][4], bh[2][4], bl[2][4];
  LOADP(ah[0], Ahp, rta, 0); LOADP(al[0], Alp, rta, 0);
  LOADP(bh[0], Bhp, ntb, 0); LOADP(bl[0], Blp, ntb, 0);
  #pragma unroll
  for (int kt = 0; kt < NKC; ++kt) {
    const int cu = kt & 1, nx = cu ^ 1;
    if (kt < NKC - 1) {
      LOADP(ah[nx], Ahp, rta, kt + 1); LOADP(al[nx], Alp, rta, kt + 1);
      LOADP(bh[nx], Bhp, ntb, kt + 1); LOADP(bl[nx], Blp, ntb, kt + 1);
    }
    #pragma unroll
    for (int m = 0; m < 4; ++m)
      #pragma unroll
      for (int n = 0; n < 4; ++n) {
        acc[m][n] = __builtin_amdgcn_mfma_f32_16x16x32_bf16(ah[cu][m], bh[cu][n], acc[m][n], 0, 0, 0);
        acc[m][n] = __builtin_amdgcn_mfma_f32_16x16x32_bf16(ah[cu][m], bl[cu][n], acc[m][n], 0, 0, 0);
        acc[m][n] = __builtin_amdgcn_mfma_f32_16x16x32_bf16(al[cu][m], bh[cu][n], acc[m][n], 0, 0, 0);
      }
  }

  #pragma unroll
  for (int n = 0; n < 4; ++n) {
    int j = j0 + n * 16 + jc;
    float bb = (j < EMB) ? bias[j] : 0.f;
    #pragma unroll
    for (int m = 0; m < 4; ++m) {
      #pragma unroll
      for (int r = 0; r < 4; ++r) {
        int R = i0 + m * 16 + rq + r;
        float v = acc[m][n][r] + bb;
        if (RELU) v = fmaxf(v, 0.f);
        if (OUTSPLIT) {
          short h, l;
          split_bf16(v, h, l);
          size_t o = pk(R, j);
          Chp[o] = h; Clp[o] = l;
        } else {
          Cf[(size_t)R * KPAD + j] = v;
        }
      }
    }
  }
}

// ---------------------------------------------------------------------------
// Per-row L2 normalize (fpad in place, fp32), packed-bf16 copy, class counts.
// ---------------------------------------------------------------------------
__global__ __launch_bounds__(256)
void normalize_count(float* __restrict__ H, short* __restrict__ FBp,
                     const int* __restrict__ labels, int* __restrict__ cnt)
{
  int wid = threadIdx.x >> 6, lane = threadIdx.x & 63;
  int r = blockIdx.x * 4 + wid;
  float* row = H + (size_t)r * KPAD;
  float v[5];
  float ss = 0.f;
  #pragma unroll
  for (int q = 0; q < 5; ++q) {
    v[q] = row[lane + 64 * q];
    ss = fmaf(v[q], v[q], ss);
  }
  #pragma unroll
  for (int off = 32; off; off >>= 1) ss += __shfl_xor(ss, off);
  float inv = 1.0f / fmaxf(sqrtf(ss), 1e-12f);
  #pragma unroll
  for (int q = 0; q < 5; ++q) {
    float nv = v[q] * inv;
    row[lane + 64 * q] = nv;
    __hip_bfloat16 b = __float2bfloat16(nv);
    FBp[pk(r, lane + 64 * q)] = *(short*)&b;
  }
  if (lane == 0) atomicAdd(&cnt[labels[r]], 1);
}

// ---------------------------------------------------------------------------
// Per-class feature sums, LDS-bucketed: grid (16 chunks, 8 class-groups).
// Each block scans 512 rows ONCE, accumulating rows of its 16 classes into
// LDS, then commits 16x320 atomics. F read exactly once per (row, group-hit)
// vs old 128x per-class rescan (1.34 GB L2 -> ~10 MB).
// ---------------------------------------------------------------------------
#define CSROWS 512
__global__ __launch_bounds__(320)
void class_sum_lds(const float* __restrict__ F, const int* __restrict__ labels,
                   float* __restrict__ cs)
{
  __shared__ float buf[16][320];
  __shared__ int lbl[CSROWS];
  int grp = blockIdx.y;
  int r0 = blockIdx.x * CSROWS;
  int d = threadIdx.x;
  #pragma unroll
  for (int i = 0; i < 16; ++i) buf[i][d] = 0.f;
  for (int i = d; i < CSROWS; i += 320) lbl[i] = labels[r0 + i];
  __syncthreads();
  for (int rr = 0; rr < CSROWS; ++rr) {
    int c = lbl[rr];
    if ((c >> 4) == grp)
      buf[c & 15][d] += F[(size_t)(r0 + rr) * KPAD + d];
  }
  __syncthreads();
  #pragma unroll
  for (int i = 0; i < 16; ++i)
    atomicAdd(&cs[(size_t)(grp * 16 + i) * KPAD + d], buf[i][d]);
}

// ---------------------------------------------------------------------------
// Symmetric MFMA Gram + exp + row/col sums. 256x256 super-tiles (4x the
// reuse of r15's 128x128: L2 load traffic 666 -> 173 MB, which was the
// bound at 60us / MfmaUtil 14%). 8 waves (2 row-halves x 4 col-quarters),
// wave tile 128x64, register double-buffered packed loads. Triangular grid,
// NTILE=32, TRI=528.
// ---------------------------------------------------------------------------
__global__ __launch_bounds__(512)
void gram_s_mfma(const short* __restrict__ FP, float* __restrict__ S)
{
  // decode linear block -> upper-tri (it, jt); verified b=0,31,32,527
  int b = blockIdx.x;
  int it = (int)((65.0f - sqrtf(4225.0f - 8.0f * (float)b)) * 0.5f);
  int base = 32 * it - (it * (it - 1)) / 2;
  if (b < base) { --it; base = 32 * it - (it * (it - 1)) / 2; }
  else { int nb = base + (32 - it); if (b >= nb) { ++it; base = nb; } }
  const int jt = it + (b - base);
  const bool offdiag = (jt > it);

  const int lane = threadIdx.x & 63;
  const int w    = threadIdx.x >> 6;   // 0..7
  const int wr   = w >> 2;             // 0..1  row half
  const int wc   = w & 3;              // 0..3  col quarter
  const int i0   = it * 256 + wr * 128;
  const int j0   = jt * 256 + wc * 64;
  const int rta  = i0 >> 4;            // 8 row-tiles (A)
  const int rtb  = j0 >> 4;            // 4 row-tiles (B)
  const int jc   = lane & 15;
  const int rq   = (lane >> 4) * 4;

  f32x4 acc[8][4] = {};
  short8 a8[2][8], b4[2][4];
  LOADP8(a8[0], FP, rta, 0); LOADP(b4[0], FP, rtb, 0);
  #pragma unroll
  for (int kt = 0; kt < NKC; ++kt) {
    const int cu = kt & 1, nx = cu ^ 1;
    if (kt < NKC - 1) {
      LOADP8(a8[nx], FP, rta, kt + 1); LOADP(b4[nx], FP, rtb, kt + 1);
    }
    #pragma unroll
    for (int m = 0; m < 8; ++m)
      #pragma unroll
      for (int n = 0; n < 4; ++n)
        acc[m][n] = __builtin_amdgcn_mfma_f32_16x16x32_bf16(a8[cu][m], b4[cu][n], acc[m][n], 0, 0, 0);
  }

  float psum[8][4] = {};   // [m][reg] row partials
  float csum[4]    = {};   // [n] col partials
  #pragma unroll
  for (int m = 0; m < 8; ++m) {
    int ibase = i0 + m * 16 + rq;
    #pragma unroll
    for (int n = 0; n < 4; ++n) {
      int j = j0 + n * 16 + jc;
      #pragma unroll
      for (int r = 0; r < 4; ++r) {
        float e = __expf((acc[m][n][r] - 1.0f) * TINV);
        e = (ibase + r == j) ? 0.0f : e;
        psum[m][r] += e;
        csum[n]    += e;
      }
    }
  }
  #pragma unroll
  for (int m = 0; m < 8; ++m)
    #pragma unroll
    for (int r = 0; r < 4; ++r) {
      float s = psum[m][r];
      s += __shfl_xor(s, 1); s += __shfl_xor(s, 2);
      s += __shfl_xor(s, 4); s += __shfl_xor(s, 8);
      if (jc == 0) atomicAdd(&S[i0 + m * 16 + rq + r], s);
    }
  if (offdiag) {
    #pragma unroll
    for (int n = 0; n < 4; ++n) {
      float s = csum[n];
      s += __shfl_xor(s, 16); s += __shfl_xor(s, 32);
      if ((lane >> 4) == 0) atomicAdd(&S[j0 + n * 16 + jc], s);
    }
  }
}

// ---------------------------------------------------------------------------
// Per-row loss -> per-block partials (no global atomics).
// ---------------------------------------------------------------------------
__global__ __launch_bounds__(256)
void loss_rows(const float* __restrict__ F, const int* __restrict__ labels,
               const int* __restrict__ cnt, const float* __restrict__ cs,
               const float* __restrict__ S, float* __restrict__ partial)
{
  __shared__ float sm[4], sc[4];
  int wid = threadIdx.x >> 6, lane = threadIdx.x & 63;
  float wsum = 0.f, wcnt = 0.f;
  #pragma unroll
  for (int rr = 0; rr < 4; ++rr) {
    int r = (blockIdx.x * 4 + wid) * 4 + rr;
    int c = labels[r];
    const float* f = F + (size_t)r * KPAD;
    const float* g = cs + (size_t)c * KPAD;
    float pd = 0.f, sd = 0.f;
    #pragma unroll
    for (int q = 0; q < 5; ++q) {
      float fv = f[lane + 64 * q];
      pd = fmaf(fv, g[lane + 64 * q], pd);
      sd = fmaf(fv, fv, sd);
    }
    #pragma unroll
    for (int off = 32; off; off >>= 1) {
      pd += __shfl_xor(pd, off);
      sd += __shfl_xor(sd, off);
    }
    int rp = cnt[c] - 1;
    if (rp > 0) {
      float sum_stab = (pd - sd) * TINV - TINV * (float)rp;
      wsum += sum_stab / (float)rp - logf(S[r]);
      wcnt += 1.0f;
    }
  }
  if (lane == 0) { sm[wid] = wsum; sc[wid] = wcnt; }
  __syncthreads();
  if (threadIdx.x == 0) {
    partial[2 * blockIdx.x]     = sm[0] + sm[1] + sm[2] + sm[3];
    partial[2 * blockIdx.x + 1] = sc[0] + sc[1] + sc[2] + sc[3];
  }
}

__global__ __launch_bounds__(256)
void finalize(const float* __restrict__ partial, float* __restrict__ out)
{
  __shared__ float ssum[4], scnt[4];
  int tid = threadIdx.x, lane = tid & 63, wid = tid >> 6;
  float s = 0.f, c = 0.f;
  for (int b = tid; b < LR_BLOCKS; b += 256) {
    s += partial[2 * b];
    c += partial[2 * b + 1];
  }
  #pragma unroll
  for (int off = 32; off; off >>= 1) {
    s += __shfl_xor(s, off);
    c += __shfl_xor(c, off);
  }
  if (lane == 0) { ssum[wid] = s; scnt[wid] = c; }
  __syncthreads();
  if (tid == 0) {
    float ts = ssum[0] + ssum[1] + ssum[2] + ssum[3];
    float tc = scnt[0] + scnt[1] + scnt[2] + scnt[3];
    out[0] = -0.1f * ts / fmaxf(tc, 1.0f);
  }
}

// ---------------------------------------------------------------------------
extern "C" void kernel_launch(void* const* d_in, const int* in_sizes, int n_in,
                              void* d_out, int out_size, void* d_ws, size_t ws_size,
                              hipStream_t stream)
{
  const float* X      = (const float*)d_in[0];
  const int*   labels = (const int*)d_in[1];
  const float* W1     = (const float*)d_in[2];
  const float* b1     = (const float*)d_in[3];
  const float* W2     = (const float*)d_in[4];
  const float* b2     = (const float*)d_in[5];
  float* out = (float*)d_out;

  const size_t NP = (size_t)NROWS * KPAD;
  const size_t WP = (size_t)KPAD * KPAD;
  short* Xh  = (short*)d_ws;
  short* Xl  = Xh + NP;
  short* Hh  = Xl + NP;
  short* Hl  = Hh + NP;
  short* FBp = Hl + NP;
  short* W1h = FBp + NP;
  short* W1l = W1h + WP;
  short* W2h = W1l + WP;
  short* W2l = W2h + WP;
  float* fpad = (float*)(W2l + WP);
  float* cs   = fpad + NP;
  float* S    = cs + (size_t)NCLS * KPAD;
  int*   cnt  = (int*)(S + NROWS);
  float* partial = (float*)(cnt + NCLS);

  size_t zbytes = ((size_t)NCLS * KPAD + NROWS + NCLS + 2 * LR_BLOCKS) * sizeof(float);
  hipMemsetAsync(cs, 0, zbytes, stream);

  conv_x <<<NROWS / 16, 320, 0, stream>>>(X, Xh, Xl);
  conv_wt<<<KPAD,  320, 0, stream>>>(W1, W1h, W1l);
  conv_wt<<<KPAD,  320, 0, stream>>>(W2, W2h, W2l);

  dim3 pg(NROWS / 64, KPAD / 64);
  gemm_mfma3p<1, 1><<<pg, 64, 0, stream>>>(Xh, Xl, W1h, W1l, b1,
                                           nullptr, Hh, Hl);
  gemm_mfma3p<0, 0><<<pg, 64, 0, stream>>>(Hh, Hl, W2h, W2l, b2,
                                           fpad, nullptr, nullptr);

  normalize_count<<<NROWS / 4, 256, 0, stream>>>(fpad, FBp, labels, cnt);

  dim3 cg(NROWS / CSROWS, 8);
  class_sum_lds<<<cg, 320, 0, stream>>>(fpad, labels, cs);

  const int NTILE = NROWS / 256;                  // 32
  const int TRI   = NTILE * (NTILE + 1) / 2;      // 528
  gram_s_mfma<<<TRI, 512, 0, stream>>>(FBp, S);

  loss_rows<<<LR_BLOCKS, 256, 0, stream>>>(fpad, labels, cnt, cs, S, partial);
  finalize<<<1, 256, 0, stream>>>(partial, out);
}

// Round 17
// 247.080 us; speedup vs baseline: 1.0536x; 1.0536x over previous
//
#include <hip/hip_runtime.h>
#include <hip/hip_bf16.h>
#include <math.h>

#define NROWS 8192
#define EMB   300
#define KPAD  320   // padded feature/K dim
#define NCLS  128
#define TINV  10.0f // 1/TEMP
#define LR_BLOCKS 512
#define NKC   10    // K-chunks of 32 (KPAD/32)
#define CH    512   // shorts per packed chunk (16 rows x 32 k)

typedef __attribute__((ext_vector_type(8))) short short8;
typedef __attribute__((ext_vector_type(4))) float f32x4;

// Packed fragment layout: chunk c = rowtile*NKC + k/32 holds 16 rows x 32 k,
// lane l reads row (l&15), k-sub (l>>4)*8 as one contiguous short8.
__device__ __forceinline__ size_t pk(int r, int k)
{
  return ((size_t)(r >> 4) * NKC + (k >> 5)) * CH
       + (size_t)(((k & 31) >> 3) * 16 + (r & 15)) * 8 + (k & 7);
}

__device__ __forceinline__ void split_bf16(float v, short& hi, short& lo)
{
  __hip_bfloat16 h = __float2bfloat16(v);
  __hip_bfloat16 l = __float2bfloat16(v - __bfloat162float(h));
  hi = *(short*)&h;
  lo = *(short*)&l;
}

// ---------------------------------------------------------------------------
// Cast X -> packed split planes. 512 blocks x 16 rows.
// ---------------------------------------------------------------------------
__global__ __launch_bounds__(320)
void conv_x(const float* __restrict__ X, short* __restrict__ Xh,
            short* __restrict__ Xl)
{
  int c = threadIdx.x;
  #pragma unroll
  for (int rr = 0; rr < 16; ++rr) {
    int r = blockIdx.x * 16 + rr;
    float v = (c < EMB) ? X[(size_t)r * EMB + c] : 0.f;
    short h, l;
    split_bf16(v, h, l);
    size_t o = pk(r, c);
    Xh[o] = h;
    Xl[o] = l;
  }
}

// ---------------------------------------------------------------------------
// Transpose+cast BOTH W1,W2 (k-major) -> packed split planes (row=n). Fused
// pair: blockIdx.y selects the matrix (saves a dispatch).
// ---------------------------------------------------------------------------
__global__ __launch_bounds__(320)
void conv_wt2(const float* __restrict__ W1, const float* __restrict__ W2,
              short* __restrict__ W1h, short* __restrict__ W1l,
              short* __restrict__ W2h, short* __restrict__ W2l)
{
  int n = blockIdx.x, k = threadIdx.x;
  const float* W = blockIdx.y ? W2 : W1;
  short* Wh = blockIdx.y ? W2h : W1h;
  short* Wl = blockIdx.y ? W2l : W1l;
  float v = (n < EMB && k < EMB) ? W[(size_t)k * EMB + n] : 0.f;
  short h, l;
  split_bf16(v, h, l);
  size_t o = pk(n, k);
  Wh[o] = h;
  Wl[o] = l;
}

#define LOADP(dst, base, rt0, kt)                                             \
  _Pragma("unroll")                                                           \
  for (int m_ = 0; m_ < 4; ++m_)                                              \
    dst[m_] = *(const short8*)((base) +                                       \
      (((size_t)(rt0) + m_) * NKC + (kt)) * CH + (size_t)lane * 8);

// ---------------------------------------------------------------------------
// Split-bf16 MFMA GEMM on packed operands (fp32-quality, Markidis 3-term).
// One wave per block, tile 64x64, grid (128, 5). Register double-buffered.
// C/D layout: col = lane&15, row = (lane>>4)*4 + reg.
// ---------------------------------------------------------------------------
template<int RELU, int OUTSPLIT>
__global__ __launch_bounds__(64)
void gemm_mfma3p(const short* __restrict__ Ahp, const short* __restrict__ Alp,
                 const short* __restrict__ Bhp, const short* __restrict__ Blp,
                 const float* __restrict__ bias,
                 float* __restrict__ Cf, short* __restrict__ Chp,
                 short* __restrict__ Clp)
{
  const int lane = threadIdx.x;
  const int i0   = blockIdx.x * 64;
  const int j0   = blockIdx.y * 64;
  const int rta  = i0 >> 4;
  const int ntb  = j0 >> 4;
  const int jc   = lane & 15;
  const int rq   = (lane >> 4) * 4;

  f32x4 acc[4][4] = {};
  short8 ah[2][4], al[2][4], bh[2][4], bl[2][4];
  LOADP(ah[0], Ahp, rta, 0); LOADP(al[0], Alp, rta, 0);
  LOADP(bh[0], Bhp, ntb, 0); LOADP(bl[0], Blp, ntb, 0);
  #pragma unroll
  for (int kt = 0; kt < NKC; ++kt) {
    const int cu = kt & 1, nx = cu ^ 1;
    if (kt < NKC - 1) {
      LOADP(ah[nx], Ahp, rta, kt + 1); LOADP(al[nx], Alp, rta, kt + 1);
      LOADP(bh[nx], Bhp, ntb, kt + 1); LOADP(bl[nx], Blp, ntb, kt + 1);
    }
    #pragma unroll
    for (int m = 0; m < 4; ++m)
      #pragma unroll
      for (int n = 0; n < 4; ++n) {
        acc[m][n] = __builtin_amdgcn_mfma_f32_16x16x32_bf16(ah[cu][m], bh[cu][n], acc[m][n], 0, 0, 0);
        acc[m][n] = __builtin_amdgcn_mfma_f32_16x16x32_bf16(ah[cu][m], bl[cu][n], acc[m][n], 0, 0, 0);
        acc[m][n] = __builtin_amdgcn_mfma_f32_16x16x32_bf16(al[cu][m], bh[cu][n], acc[m][n], 0, 0, 0);
      }
  }

  #pragma unroll
  for (int n = 0; n < 4; ++n) {
    int j = j0 + n * 16 + jc;
    float bb = (j < EMB) ? bias[j] : 0.f;
    #pragma unroll
    for (int m = 0; m < 4; ++m) {
      #pragma unroll
      for (int r = 0; r < 4; ++r) {
        int R = i0 + m * 16 + rq + r;
        float v = acc[m][n][r] + bb;
        if (RELU) v = fmaxf(v, 0.f);
        if (OUTSPLIT) {
          short h, l;
          split_bf16(v, h, l);
          size_t o = pk(R, j);
          Chp[o] = h; Clp[o] = l;
        } else {
          Cf[(size_t)R * KPAD + j] = v;
        }
      }
    }
  }
}

// ---------------------------------------------------------------------------
// Per-row L2 normalize (fpad in place, fp32), packed-bf16 copy, class counts.
// ---------------------------------------------------------------------------
__global__ __launch_bounds__(256)
void normalize_count(float* __restrict__ H, short* __restrict__ FBp,
                     const int* __restrict__ labels, int* __restrict__ cnt)
{
  int wid = threadIdx.x >> 6, lane = threadIdx.x & 63;
  int r = blockIdx.x * 4 + wid;
  float* row = H + (size_t)r * KPAD;
  float v[5];
  float ss = 0.f;
  #pragma unroll
  for (int q = 0; q < 5; ++q) {
    v[q] = row[lane + 64 * q];
    ss = fmaf(v[q], v[q], ss);
  }
  #pragma unroll
  for (int off = 32; off; off >>= 1) ss += __shfl_xor(ss, off);
  float inv = 1.0f / fmaxf(sqrtf(ss), 1e-12f);
  #pragma unroll
  for (int q = 0; q < 5; ++q) {
    float nv = v[q] * inv;
    row[lane + 64 * q] = nv;
    __hip_bfloat16 b = __float2bfloat16(nv);
    FBp[pk(r, lane + 64 * q)] = *(short*)&b;
  }
  if (lane == 0) atomicAdd(&cnt[labels[r]], 1);
}

// ---------------------------------------------------------------------------
// Per-class feature sums, LDS-bucketed: grid (16 chunks, 8 class-groups).
// ---------------------------------------------------------------------------
#define CSROWS 512
__global__ __launch_bounds__(320)
void class_sum_lds(const float* __restrict__ F, const int* __restrict__ labels,
                   float* __restrict__ cs)
{
  __shared__ float buf[16][320];
  __shared__ int lbl[CSROWS];
  int grp = blockIdx.y;
  int r0 = blockIdx.x * CSROWS;
  int d = threadIdx.x;
  #pragma unroll
  for (int i = 0; i < 16; ++i) buf[i][d] = 0.f;
  for (int i = d; i < CSROWS; i += 320) lbl[i] = labels[r0 + i];
  __syncthreads();
  for (int rr = 0; rr < CSROWS; ++rr) {
    int c = lbl[rr];
    if ((c >> 4) == grp)
      buf[c & 15][d] += F[(size_t)(r0 + rr) * KPAD + d];
  }
  __syncthreads();
  #pragma unroll
  for (int i = 0; i < 16; ++i)
    atomicAdd(&cs[(size_t)(grp * 16 + i) * KPAD + d], buf[i][d]);
}

// ---------------------------------------------------------------------------
// Symmetric MFMA Gram + exp + row/col sums. ONE WAVE per block, 64x64 tile,
// triangular grid over 128 tiles (8256 blocks). r16's 8-wave 256-tile
// REGRESSED (69us, Occ 15%, FETCH 3x): latency-bound, needed more
// independent waves, not more per-block reuse. 1-wave blocks maximize
// scheduler packing. Same total L2 traffic as r15's 60us config.
// ---------------------------------------------------------------------------
__global__ __launch_bounds__(64)
void gram_s_mfma(const short* __restrict__ FP, float* __restrict__ S)
{
  // decode linear block -> upper-tri (it, jt), NTILE=128.
  // verified b=0, 127, 128, 8255.
  int b = blockIdx.x;
  int it = (int)((257.0f - sqrtf(66049.0f - 8.0f * (float)b)) * 0.5f);
  int base = 128 * it - (it * (it - 1)) / 2;
  if (b < base) { --it; base = 128 * it - (it * (it - 1)) / 2; }
  else { int nb = base + (128 - it); if (b >= nb) { ++it; base = nb; } }
  const int jt = it + (b - base);
  const bool offdiag = (jt > it);

  const int lane = threadIdx.x;
  const int i0   = it * 64;
  const int j0   = jt * 64;
  const int rta  = i0 >> 4;
  const int rtb  = j0 >> 4;
  const int jc   = lane & 15;
  const int rq   = (lane >> 4) * 4;

  f32x4 acc[4][4] = {};
  short8 ab[2][4], bb_[2][4];
  LOADP(ab[0], FP, rta, 0); LOADP(bb_[0], FP, rtb, 0);
  #pragma unroll
  for (int kt = 0; kt < NKC; ++kt) {
    const int cu = kt & 1, nx = cu ^ 1;
    if (kt < NKC - 1) {
      LOADP(ab[nx], FP, rta, kt + 1); LOADP(bb_[nx], FP, rtb, kt + 1);
    }
    #pragma unroll
    for (int m = 0; m < 4; ++m)
      #pragma unroll
      for (int n = 0; n < 4; ++n)
        acc[m][n] = __builtin_amdgcn_mfma_f32_16x16x32_bf16(ab[cu][m], bb_[cu][n], acc[m][n], 0, 0, 0);
  }

  float psum[4][4] = {};   // [m][reg] row partials
  float csum[4]    = {};   // [n] col partials
  #pragma unroll
  for (int m = 0; m < 4; ++m) {
    int ibase = i0 + m * 16 + rq;
    #pragma unroll
    for (int n = 0; n < 4; ++n) {
      int j = j0 + n * 16 + jc;
      #pragma unroll
      for (int r = 0; r < 4; ++r) {
        float e = __expf((acc[m][n][r] - 1.0f) * TINV);
        e = (ibase + r == j) ? 0.0f : e;
        psum[m][r] += e;
        csum[n]    += e;
      }
    }
  }
  #pragma unroll
  for (int m = 0; m < 4; ++m)
    #pragma unroll
    for (int r = 0; r < 4; ++r) {
      float s = psum[m][r];
      s += __shfl_xor(s, 1); s += __shfl_xor(s, 2);
      s += __shfl_xor(s, 4); s += __shfl_xor(s, 8);
      if (jc == 0) atomicAdd(&S[i0 + m * 16 + rq + r], s);
    }
  if (offdiag) {
    #pragma unroll
    for (int n = 0; n < 4; ++n) {
      float s = csum[n];
      s += __shfl_xor(s, 16); s += __shfl_xor(s, 32);
      if ((lane >> 4) == 0) atomicAdd(&S[j0 + n * 16 + jc], s);
    }
  }
}

// ---------------------------------------------------------------------------
// Per-row loss -> per-block partials (no global atomics).
// ---------------------------------------------------------------------------
__global__ __launch_bounds__(256)
void loss_rows(const float* __restrict__ F, const int* __restrict__ labels,
               const int* __restrict__ cnt, const float* __restrict__ cs,
               const float* __restrict__ S, float* __restrict__ partial)
{
  __shared__ float sm[4], sc[4];
  int wid = threadIdx.x >> 6, lane = threadIdx.x & 63;
  float wsum = 0.f, wcnt = 0.f;
  #pragma unroll
  for (int rr = 0; rr < 4; ++rr) {
    int r = (blockIdx.x * 4 + wid) * 4 + rr;
    int c = labels[r];
    const float* f = F + (size_t)r * KPAD;
    const float* g = cs + (size_t)c * KPAD;
    float pd = 0.f, sd = 0.f;
    #pragma unroll
    for (int q = 0; q < 5; ++q) {
      float fv = f[lane + 64 * q];
      pd = fmaf(fv, g[lane + 64 * q], pd);
      sd = fmaf(fv, fv, sd);
    }
    #pragma unroll
    for (int off = 32; off; off >>= 1) {
      pd += __shfl_xor(pd, off);
      sd += __shfl_xor(sd, off);
    }
    int rp = cnt[c] - 1;
    if (rp > 0) {
      float sum_stab = (pd - sd) * TINV - TINV * (float)rp;
      wsum += sum_stab / (float)rp - logf(S[r]);
      wcnt += 1.0f;
    }
  }
  if (lane == 0) { sm[wid] = wsum; sc[wid] = wcnt; }
  __syncthreads();
  if (threadIdx.x == 0) {
    partial[2 * blockIdx.x]     = sm[0] + sm[1] + sm[2] + sm[3];
    partial[2 * blockIdx.x + 1] = sc[0] + sc[1] + sc[2] + sc[3];
  }
}

__global__ __launch_bounds__(256)
void finalize(const float* __restrict__ partial, float* __restrict__ out)
{
  __shared__ float ssum[4], scnt[4];
  int tid = threadIdx.x, lane = tid & 63, wid = tid >> 6;
  float s = 0.f, c = 0.f;
  for (int b = tid; b < LR_BLOCKS; b += 256) {
    s += partial[2 * b];
    c += partial[2 * b + 1];
  }
  #pragma unroll
  for (int off = 32; off; off >>= 1) {
    s += __shfl_xor(s, off);
    c += __shfl_xor(c, off);
  }
  if (lane == 0) { ssum[wid] = s; scnt[wid] = c; }
  __syncthreads();
  if (tid == 0) {
    float ts = ssum[0] + ssum[1] + ssum[2] + ssum[3];
    float tc = scnt[0] + scnt[1] + scnt[2] + scnt[3];
    out[0] = -0.1f * ts / fmaxf(tc, 1.0f);
  }
}

// ---------------------------------------------------------------------------
extern "C" void kernel_launch(void* const* d_in, const int* in_sizes, int n_in,
                              void* d_out, int out_size, void* d_ws, size_t ws_size,
                              hipStream_t stream)
{
  const float* X      = (const float*)d_in[0];
  const int*   labels = (const int*)d_in[1];
  const float* W1     = (const float*)d_in[2];
  const float* b1     = (const float*)d_in[3];
  const float* W2     = (const float*)d_in[4];
  const float* b2     = (const float*)d_in[5];
  float* out = (float*)d_out;

  const size_t NP = (size_t)NROWS * KPAD;
  const size_t WP = (size_t)KPAD * KPAD;
  short* Xh  = (short*)d_ws;
  short* Xl  = Xh + NP;
  short* Hh  = Xl + NP;
  short* Hl  = Hh + NP;
  short* FBp = Hl + NP;
  short* W1h = FBp + NP;
  short* W1l = W1h + WP;
  short* W2h = W1l + WP;
  short* W2l = W2h + WP;
  float* fpad = (float*)(W2l + WP);
  float* cs   = fpad + NP;
  float* S    = cs + (size_t)NCLS * KPAD;
  int*   cnt  = (int*)(S + NROWS);
  float* partial = (float*)(cnt + NCLS);

  size_t zbytes = ((size_t)NCLS * KPAD + NROWS + NCLS + 2 * LR_BLOCKS) * sizeof(float);
  hipMemsetAsync(cs, 0, zbytes, stream);

  conv_x <<<NROWS / 16, 320, 0, stream>>>(X, Xh, Xl);
  dim3 wg(KPAD, 2);
  conv_wt2<<<wg, 320, 0, stream>>>(W1, W2, W1h, W1l, W2h, W2l);

  dim3 pg(NROWS / 64, KPAD / 64);
  gemm_mfma3p<1, 1><<<pg, 64, 0, stream>>>(Xh, Xl, W1h, W1l, b1,
                                           nullptr, Hh, Hl);
  gemm_mfma3p<0, 0><<<pg, 64, 0, stream>>>(Hh, Hl, W2h, W2l, b2,
                                           fpad, nullptr, nullptr);

  normalize_count<<<NROWS / 4, 256, 0, stream>>>(fpad, FBp, labels, cnt);

  dim3 cg(NROWS / CSROWS, 8);
  class_sum_lds<<<cg, 320, 0, stream>>>(fpad, labels, cs);

  const int NTILE = NROWS / 64;                   // 128
  const int TRI   = NTILE * (NTILE + 1) / 2;      // 8256
  gram_s_mfma<<<TRI, 64, 0, stream>>>(FBp, S);

  loss_rows<<<LR_BLOCKS, 256, 0, stream>>>(fpad, labels, cnt, cs, S, partial);
  finalize<<<1, 256, 0, stream>>>(partial, out);
}